// Round 6
// baseline (59.252 us; speedup 1.0000x reference)
//
#include <hip/hip_runtime.h>
#include <hip/hip_bf16.h>

// Problem geometry (fixed by the reference):
//   x: [B=8, C=32, 4096, 64] fp32  -> flat [256 slabs][N=262144]
//   distance:   perm of N=64^3      (voxel v holds x element distance[v])
//   coordinate: perm of NP=32^3     (output j comes from pooled voxel coordinate[j])
//   out[bc][j] = max over the 2x2x2 block of pooled voxel coordinate[j]
//
// Strategy (R2->R6): scatter via precomputed u16 target table tgt[i] (every x
// element lands in exactly one output slot; maps are bijective). Per slab:
// stream x coalesced (nontemporal), LDS-atomicMax into a 128 KiB accumulator,
// decode + coalesced nontemporal store. R5 added raw-s_barrier (no vmcnt
// drain), pre-init first load chunk, CH=8 ping-pong. R6: setup kernel
// parallelized 8x (one thread per (output, corner) — scatter is latency-bound).

#define N_VOX   262144   // 64^3
#define N_POOL  32768    // 32^3
#define N_BC    256      // B*C

typedef float          f32x4 __attribute__((ext_vector_type(4)));
typedef unsigned int   u32x4 __attribute__((ext_vector_type(4)));
typedef unsigned short u16x4 __attribute__((ext_vector_type(4)));

// Monotone fp32 <-> u32 encoding so unsigned max == float max.
__device__ __forceinline__ unsigned enc_f32(float f) {
    unsigned u = __float_as_uint(f);
    return u ^ (((int)u >> 31) | 0x80000000u);  // 2 VALU ops
}
__device__ __forceinline__ float dec_f32(unsigned u) {
    return __uint_as_float(u ^ (~((int)u >> 31) | 0x80000000u));
}

// ---------------------------------------------------------------------------
// Setup: one thread per (output j, corner e). tgt[distance[child(coord[j],e)]]
// = j. Each tgt entry written exactly once (bijections) -> race-free.
// 262144 threads: 8x the parallelism of the per-j version (latency-bound).
__global__ __launch_bounds__(256) void build_tgt_direct(const int* __restrict__ distance,
                                                        const int* __restrict__ coordinate,
                                                        unsigned short* __restrict__ tgt) {
    int idx = blockIdx.x * 256 + threadIdx.x;
    int j = idx >> 3, e = idx & 7;
    int p = coordinate[j];  // 8-way broadcast across consecutive threads (cache hit)
    int base = ((p >> 10) << 1) * 4096 + (((p >> 5) & 31) << 1) * 64 + ((p & 31) << 1);
    int off = (e & 1) + ((e & 2) ? 64 : 0) + ((e & 4) ? 4096 : 0);
    tgt[distance[base + off]] = (unsigned short)j;
}

// ---------------------------------------------------------------------------
// Main: one 1024-thread workgroup per slab. 128 KiB LDS accumulator.
// 64 f32x4-iterations/thread, chunked CH=8, ping-pong double-buffered.
#define CH   8                       // f32x4-iters per chunk
#define NCH  (N_VOX / 4 / 1024 / CH) // 8 chunks

// LDS-only barrier: drain DS ops, then raw s_barrier (no vmcnt(0) drain, so
// in-flight global loads keep flying across the barrier).
__device__ __forceinline__ void lds_barrier() {
    asm volatile("s_waitcnt lgkmcnt(0)" ::: "memory");
    __builtin_amdgcn_s_barrier();
}

__global__ __launch_bounds__(1024) void pool_scatter(const float* __restrict__ x,
                                                     const unsigned short* __restrict__ tgt,
                                                     float* __restrict__ out) {
    __shared__ unsigned int acc[N_POOL];  // 128 KiB
    const int tid = threadIdx.x;
    const int bc  = blockIdx.x;

    const f32x4* x4 = (const f32x4*)(x + (size_t)bc * N_VOX);
    const u16x4* t4 = (const u16x4*)tgt;

    f32x4 xa[CH], xb[CH];
    u16x4 ta[CH], tb[CH];

#define LOADC(XV, TV, c)                                                     \
    {                                                                        \
        _Pragma("unroll")                                                    \
        for (int u = 0; u < CH; ++u) {                                       \
            int i = ((c) * CH + u) * 1024 + tid;                             \
            XV[u] = __builtin_nontemporal_load(&x4[i]);                      \
            TV[u] = t4[i];                                                   \
        }                                                                    \
    }

#define PROC(XV, TV)                                                         \
    {                                                                        \
        _Pragma("unroll")                                                    \
        for (int u = 0; u < CH; ++u) {                                       \
            atomicMax(&acc[TV[u].x], enc_f32(XV[u].x));                      \
            atomicMax(&acc[TV[u].y], enc_f32(XV[u].y));                      \
            atomicMax(&acc[TV[u].z], enc_f32(XV[u].z));                      \
            atomicMax(&acc[TV[u].w], enc_f32(XV[u].w));                      \
        }                                                                    \
    }

    // Issue the first chunk's loads before LDS init: HBM ramp overlaps init.
    LOADC(xa, ta, 0);

    // Vectorized init: 8 x u32x4 stores per thread (encoded "very negative").
    u32x4* a4i = (u32x4*)acc;
    const u32x4 z4 = {0u, 0u, 0u, 0u};
    #pragma unroll
    for (int k = 0; k < N_POOL / 4 / 1024; ++k)
        a4i[k * 1024 + tid] = z4;
    lds_barrier();

    for (int c = 0; c < NCH; c += 2) {
        LOADC(xb, tb, c + 1);
        PROC(xa, ta);
        if (c + 2 < NCH) LOADC(xa, ta, c + 2);
        PROC(xb, tb);
    }
    lds_barrier();

    // Epilogue: u32x4 acc read, decode, nontemporal f32x4 store.
    const u32x4* a4 = (const u32x4*)acc;
    f32x4* o4 = (f32x4*)(out + (size_t)bc * N_POOL);
    #pragma unroll
    for (int k = 0; k < N_POOL / 4 / 1024; ++k) {
        int j4 = k * 1024 + tid;
        u32x4 a = a4[j4];
        f32x4 v;
        v.x = dec_f32(a.x);
        v.y = dec_f32(a.y);
        v.z = dec_f32(a.z);
        v.w = dec_f32(a.w);
        __builtin_nontemporal_store(v, &o4[j4]);
    }
}

// ---------------------------------------------------------------------------
// Fallback (ws too small): gather-on-the-fly kernel (correct, slower).
__global__ __launch_bounds__(256) void pool_gather_fly(const float* __restrict__ x,
                                                       const int* __restrict__ distance,
                                                       const int* __restrict__ coordinate,
                                                       float* __restrict__ out) {
    int lb   = blockIdx.x;
    int xcd  = lb & 7;
    int q    = lb >> 3;
    int slab = q >> 7;
    int jb   = q & 127;
    int bc   = xcd + (slab << 3);
    int j    = (jb << 8) + threadIdx.x;

    int p  = coordinate[j];
    int a0 = p >> 10, a1 = (p >> 5) & 31, a2 = p & 31;
    int base = (a0 << 1) * 4096 + (a1 << 1) * 64 + (a2 << 1);

    const float* xb = x + (size_t)bc * N_VOX;
    float v = xb[distance[base]];
    v = fmaxf(v, xb[distance[base + 1]]);
    v = fmaxf(v, xb[distance[base + 64]]);
    v = fmaxf(v, xb[distance[base + 65]]);
    v = fmaxf(v, xb[distance[base + 4096]]);
    v = fmaxf(v, xb[distance[base + 4097]]);
    v = fmaxf(v, xb[distance[base + 4160]]);
    v = fmaxf(v, xb[distance[base + 4161]]);

    out[(size_t)bc * N_POOL + j] = v;
}

extern "C" void kernel_launch(void* const* d_in, const int* in_sizes, int n_in,
                              void* d_out, int out_size, void* d_ws, size_t ws_size,
                              hipStream_t stream) {
    const float* x          = (const float*)d_in[0];
    const int*   distance   = (const int*)d_in[1];
    const int*   coordinate = (const int*)d_in[2];
    float*       out        = (float*)d_out;

    const size_t need = (size_t)N_VOX * sizeof(unsigned short);  // tgt: 512 KiB

    if (ws_size >= need) {
        unsigned short* tgt = (unsigned short*)d_ws;
        build_tgt_direct<<<N_VOX / 256, 256, 0, stream>>>(distance, coordinate, tgt);
        pool_scatter<<<N_BC, 1024, 0, stream>>>(x, tgt, out);
    } else {
        pool_gather_fly<<<N_BC * 128, 256, 0, stream>>>(x, distance, coordinate, out);
    }
}